// Round 2
// 1668.907 us; speedup vs baseline: 1.0199x; 1.0199x over previous
//
#include <hip/hip_runtime.h>
#include <stdint.h>

// CouncilLayer: out[n,c] = sum_e softmax(x@gw+gb)[n,e] * (gelu(x@w1[e]+b1[e]) @ w2[e] + b2[e])[c]
// N=2048 tokens, C=768, E=32, H=3072. fp32 in/out; bf16 MFMA compute.
//
// R4 (= R3 resubmit + hardening; R3 bench was an infra failure, no verdict):
// 256x256 / BK=64 / 8-wave "8-phase" GEMM (learn_hip m201 template):
//  - double-buffered 128 KiB dynamic LDS, global_load_lds width-16 staging
//  - counted s_waitcnt vmcnt(8) in the main loop (never 0), barriers never drain VMEM
//  - per-phase {ds_read frags; s_barrier; lgkmcnt(0); sched_barrier; setprio(1); 16 MFMA; setprio(0); s_barrier}
//  - XOR-swizzled LDS images (same pack format as R2, measured 0 bank conflicts)
//  - gemm2 split-K = 1 expert per blockIdx.z; gate folded into fp32 reduce
//  - hipFuncSetAttribute called unconditionally each launch (capture-safe, no stream ops)

typedef unsigned short u16;
typedef __attribute__((ext_vector_type(8))) short short8;     // bf16 MFMA A/B frag
typedef __attribute__((ext_vector_type(8))) unsigned short ushort8v;
typedef __attribute__((ext_vector_type(4))) unsigned short ushort4v;
typedef __attribute__((ext_vector_type(4))) float float4v;

#define DEV __device__ __forceinline__

DEV u16 rne_bf16(float f) {
  union { float f; uint32_t u; } v; v.f = f;
  uint32_t u = v.u;
  u += 0x7FFFu + ((u >> 16) & 1u);
  return (u16)(u >> 16);
}

// branchless erf, Abramowitz-Stegun 7.1.26, |err| <= 1.5e-7
DEV float fast_erf(float x) {
  float ax = __builtin_fabsf(x);
  float t = __builtin_amdgcn_rcpf(__builtin_fmaf(0.3275911f, ax, 1.0f));
  float p = t * (0.254829592f + t * (-0.284496736f + t * (1.421413741f +
            t * (-1.453152027f + t * 1.061405429f))));
  float r = 1.0f - p * __expf(-ax * ax);
  return __builtin_copysignf(r, x);
}

DEV void load_lds16(const void* g, void* l) {
  __builtin_amdgcn_global_load_lds(
      (const __attribute__((address_space(1))) unsigned int*)g,
      (__attribute__((address_space(3))) unsigned int*)l,
      16, 0, 0);
}

// ---------------- small kernels ----------------

__global__ void cvt_x_kernel(const float* __restrict__ x, u16* __restrict__ xb, int n4) {
  int i = blockIdx.x * 256 + threadIdx.x;
  if (i >= n4) return;
  float4v v = *(const float4v*)(x + (size_t)i * 4);
  ushort4v o;
  o[0] = rne_bf16(v[0]); o[1] = rne_bf16(v[1]);
  o[2] = rne_bf16(v[2]); o[3] = rne_bf16(v[3]);
  *(ushort4v*)(xb + (size_t)i * 4) = o;
}

__global__ void gate_kernel(const float* __restrict__ x, const float* __restrict__ gw,
                            const float* __restrict__ gb, float* __restrict__ gates) {
  int lane = threadIdx.x;
  int tok = blockIdx.x * 2 + (lane >> 5);
  int e = lane & 31;
  const float* xr = x + (size_t)tok * 768;
  float s = gb[e];
  #pragma unroll 4
  for (int c = 0; c < 768; ++c) s += xr[c] * gw[c * 32 + e];
  float mx = s;
  #pragma unroll
  for (int o = 16; o >= 1; o >>= 1) mx = fmaxf(mx, __shfl_xor(mx, o, 32));
  float ex = __expf(s - mx);
  float sum = ex;
  #pragma unroll
  for (int o = 16; o >= 1; o >>= 1) sum += __shfl_xor(sum, o, 32);
  gates[tok * 32 + e] = ex / sum;
}

__global__ void bias_out_kernel(const float* __restrict__ gates, const float* __restrict__ b2,
                                float* __restrict__ out) {
  int idx = blockIdx.x * 256 + threadIdx.x;
  int n = idx / 768;
  int c = idx - n * 768;
  const float* g = gates + n * 32;
  float s = 0.f;
  #pragma unroll
  for (int e = 0; e < 32; ++e) s += g[e] * b2[e * 768 + c];
  out[idx] = s;
}

// out += sum_z gates[n, e_base+z] * part[z]   (parts are per-expert, gate applied here in fp32)
__global__ void reduce_kernel(const float* __restrict__ part, const float* __restrict__ gates,
                              float* __restrict__ out, int zn, int e_base, int n4) {
  int i = blockIdx.x * 256 + threadIdx.x;
  if (i >= n4) return;
  int n = (i << 2) / 768;
  const float* g = gates + n * 32 + e_base;
  float4v o = *(const float4v*)(out + (size_t)i * 4);
  #pragma unroll 4
  for (int z = 0; z < zn; ++z) {
    float gz = g[z];
    float4v p = *(const float4v*)(part + (size_t)z * (2048L * 768) + (size_t)i * 4);
    o[0] += gz * p[0]; o[1] += gz * p[1]; o[2] += gz * p[2]; o[3] += gz * p[3];
  }
  *(float4v*)(out + (size_t)i * 4) = o;
}

// pack fp32 [K x N] into bf16 tiles [nt][kt][n(128)][k(64)], 16KB/tile,
// with 16B-chunk XOR swizzle: chunk c of row n stored at slot c^(n&7).
__global__ void pack_b_kernel(const float* __restrict__ in, u16* __restrict__ out,
                              int ktiles, int n_per_e, long e_stride, int row_stride) {
  int kt = blockIdx.x, nt = blockIdx.y;
  int n0 = nt * 128;
  int e = n0 / n_per_e;
  int nl = n0 - e * n_per_e;
  const float* src = in + (long)e * e_stride + (long)kt * 64 * row_stride + nl;

  __shared__ u16 lds[64 * 136];
  int t = threadIdx.x;
  {
    int k = t >> 2, nq = (t & 3) * 32;
    const float* p = src + (long)k * row_stride + nq;
    u16 tmp[32];
    #pragma unroll
    for (int i = 0; i < 32; i += 4) {
      float4v v = *(const float4v*)(p + i);
      tmp[i] = rne_bf16(v[0]); tmp[i + 1] = rne_bf16(v[1]);
      tmp[i + 2] = rne_bf16(v[2]); tmp[i + 3] = rne_bf16(v[3]);
    }
    #pragma unroll
    for (int i = 0; i < 32; i += 8)
      *(ushort8v*)&lds[k * 136 + nq + i] = *(ushort8v*)&tmp[i];
  }
  __syncthreads();
  {
    int n = t >> 1, half = t & 1;
    u16 v[32];
    #pragma unroll
    for (int j = 0; j < 32; ++j) v[j] = lds[(half * 32 + j) * 136 + n];
    u16* tile = out + ((long)nt * ktiles + kt) * 8192 + n * 64;
    int sw = n & 7;
    #pragma unroll
    for (int cc = 0; cc < 4; ++cc) {
      int c = half * 4 + cc;
      *(ushort8v*)(tile + ((c ^ sw) * 8)) = *(ushort8v*)&v[cc * 8];
    }
  }
}

// ---------------- 256x256 8-phase GEMM ----------------
// 8 waves (2M x 4N), per-wave 128x64 output = acc[8][4] 16x16 frags (128 AGPR).
// LDS: dbuf x (A 256x64 + B 256x64) bf16 = 131072 B dynamic.
// A: bf16 row-major [M x Ktot], staged with lane-swizzled global source -> XOR image.
// B: pre-packed swizzled 128x64 tiles; two tiles side by side = linear [256][64] image.
// MODE 1: out = bf16(gelu(acc + b1)) -> hbuf.  MODE 2: fp32 per-expert partial store.
template <int MODE>
__global__ __launch_bounds__(512, 2) void gemm256(
    const u16* __restrict__ A, long lda,
    const u16* __restrict__ Bp, int ktt, int ktb, int nkt,
    void* __restrict__ outp, long ldo,
    const float* __restrict__ b1g, long zstride) {

  extern __shared__ u16 sm[];
  // layout (bytes): [A0 0..32K][B0 32..64K][A1 64..96K][B1 96..128K]
  u16* const Abuf[2] = { sm,         sm + 32768 };
  u16* const Bbuf[2] = { sm + 16384, sm + 49152 };

  const int tid  = threadIdx.x;
  const int wave = tid >> 6, lane = tid & 63;
  const int wr = wave >> 2, wc = wave & 3;           // 2M x 4N wave grid
  const int bh = wave >> 2, w4 = wave & 3;           // B staging: half + quarter
  const int lr = lane >> 3, l8 = lane & 7;           // A staging row/chunk
  const int frow = lane & 15, fq = lane >> 4, fx = lane & 7;
  const int m0 = blockIdx.x * 256;
  const int nt0 = blockIdx.y * 2;
  const int kt_begin = blockIdx.z * ktb;

  // A staging: wave stages rows wave*32 + j*8 + lr; global chunk (l8^lr) -> linear LDS slot l8.
  // (global_load_lds dest = wave-uniform base + lane*16B; image[row][slot] = global[row][slot^(row&7)])
  const u16* gA = A + (long)(m0 + wave * 32 + lr) * lda + (long)kt_begin * 64 + (l8 ^ lr) * 8;
  // B staging: straight 16KB tile copies (pack output already is the swizzled LDS image).
  const u16* gB = Bp + ((long)(nt0 + bh) * ktt + kt_begin) * 8192 + w4 * 2048 + lane * 8;
  u16* const ldsA[2] = { Abuf[0] + wave * 2048, Abuf[1] + wave * 2048 };
  u16* const ldsB[2] = { Bbuf[0] + bh * 8192 + w4 * 2048, Bbuf[1] + bh * 8192 + w4 * 2048 };

  float4v acc[8][4] = {};
  short8 af[4][2], bf[2][2];

#define STAGE(p) { \
    _Pragma("unroll") for (int j = 0; j < 4; ++j) { \
      load_lds16(gA + (long)j * 8 * lda, ldsA[p] + j * 512); \
      load_lds16(gB + j * 512,           ldsB[p] + j * 512); } \
    gA += 64; gB += 8192; }

#define RD_A(p, QM) \
    _Pragma("unroll") for (int mf = 0; mf < 4; ++mf) \
    _Pragma("unroll") for (int ks = 0; ks < 2; ++ks) \
      af[mf][ks] = *(const short8*)&Abuf[p][(wr * 128 + (QM) * 64 + mf * 16 + frow) * 64 + \
                                            (((ks * 4 + fq) ^ fx) * 8)];

#define RD_B(p, QN) \
    _Pragma("unroll") for (int nf = 0; nf < 2; ++nf) \
    _Pragma("unroll") for (int ks = 0; ks < 2; ++ks) \
      bf[nf][ks] = *(const short8*)&Bbuf[p][(wc * 64 + (QN) * 32 + nf * 16 + frow) * 64 + \
                                            (((ks * 4 + fq) ^ fx) * 8)];

#define MMQ(QM, QN) { \
    __builtin_amdgcn_s_barrier(); \
    asm volatile("s_waitcnt lgkmcnt(0)" ::: "memory"); \
    __builtin_amdgcn_sched_barrier(0); \
    __builtin_amdgcn_s_setprio(1); \
    _Pragma("unroll") for (int mf = 0; mf < 4; ++mf) \
    _Pragma("unroll") for (int nf = 0; nf < 2; ++nf) \
    _Pragma("unroll") for (int ks = 0; ks < 2; ++ks) \
      acc[(QM) * 4 + mf][(QN) * 2 + nf] = __builtin_amdgcn_mfma_f32_16x16x32_bf16( \
          af[mf][ks], bf[nf][ks], acc[(QM) * 4 + mf][(QN) * 2 + nf], 0, 0, 0); \
    __builtin_amdgcn_s_setprio(0); \
    __builtin_amdgcn_s_barrier(); }

  // 4 quadrant phases per K-tile; A frags reused across qn, B frags across qm.
#define HALF(p) { RD_A(p, 0); RD_B(p, 0); MMQ(0, 0); \
                  RD_B(p, 1);             MMQ(0, 1); \
                  RD_A(p, 1);             MMQ(1, 1); \
                  RD_B(p, 0);             MMQ(1, 0); }

#define WAITV8 { asm volatile("s_waitcnt vmcnt(8)" ::: "memory"); \
                 __builtin_amdgcn_s_barrier(); __builtin_amdgcn_sched_barrier(0); }
#define WAITV0 { asm volatile("s_waitcnt vmcnt(0)" ::: "memory"); \
                 __builtin_amdgcn_s_barrier(); __builtin_amdgcn_sched_barrier(0); }

  // vmcnt ledger (8 loads per STAGE):
  //   prologue: STAGE(0) STAGE(1)        -> 16 outstanding
  //   loop i:   WAITV8 (tile 2i landed, 8 left) HALF(0) STAGE(0) -> 16
  //             WAITV8 (tile 2i+1 landed)       HALF(1) STAGE(1) -> 16
  //   tail:     WAITV8 HALF(0)  WAITV0 HALF(1)  -> 0
  STAGE(0); STAGE(1);
  const int niter = nkt >> 1;
  for (int i = 0; i < niter - 1; ++i) {
    WAITV8;
    HALF(0);
    STAGE(0);
    WAITV8;
    HALF(1);
    STAGE(1);
  }
  WAITV8; HALF(0);
  WAITV0; HALF(1);

#undef STAGE
#undef RD_A
#undef RD_B
#undef MMQ
#undef HALF
#undef WAITV8
#undef WAITV0

  if (MODE == 1) {
    const int n0 = nt0 * 128;                 // column within [G*H]
    const int e_loc = n0 / 3072;
    const int h0 = n0 - e_loc * 3072;
    const float* be = b1g + (long)e_loc * 3072 + h0;
    u16* out = (u16*)outp;
    #pragma unroll
    for (int qn = 0; qn < 2; ++qn)
      #pragma unroll
      for (int nf = 0; nf < 2; ++nf) {
        const int ncol = wc * 64 + qn * 32 + nf * 16 + frow;
        const float bv = be[ncol];
        #pragma unroll
        for (int qm = 0; qm < 2; ++qm)
          #pragma unroll
          for (int mf = 0; mf < 4; ++mf) {
            u16* op = out + (long)(m0 + wr * 128 + qm * 64 + mf * 16 + fq * 4) * ldo + (n0 + ncol);
            #pragma unroll
            for (int r = 0; r < 4; ++r) {
              float v = acc[qm * 4 + mf][qn * 2 + nf][r] + bv;
              v = 0.5f * v * (1.0f + fast_erf(v * 0.70710678118654752440f));
              op[(long)r * ldo] = rne_bf16(v);
            }
          }
      }
  } else {
    float* out = (float*)outp + (long)blockIdx.z * zstride;
    const int n0 = nt0 * 128;
    #pragma unroll
    for (int qn = 0; qn < 2; ++qn)
      #pragma unroll
      for (int nf = 0; nf < 2; ++nf) {
        const int ncol = n0 + wc * 64 + qn * 32 + nf * 16 + frow;
        #pragma unroll
        for (int qm = 0; qm < 2; ++qm)
          #pragma unroll
          for (int mf = 0; mf < 4; ++mf) {
            float* op = out + (long)(m0 + wr * 128 + qm * 64 + mf * 16 + fq * 4) * ldo + ncol;
            #pragma unroll
            for (int r = 0; r < 4; ++r) op[(long)r * ldo] = acc[qm * 4 + mf][qn * 2 + nf][r];
          }
      }
  }
}

// ---------------- launch ----------------

extern "C" void kernel_launch(void* const* d_in, const int* in_sizes, int n_in,
                              void* d_out, int out_size, void* d_ws, size_t ws_size,
                              hipStream_t stream) {
  (void)in_sizes; (void)n_in; (void)out_size;
  const float* x  = (const float*)d_in[0];
  const float* gw = (const float*)d_in[1];
  const float* gb = (const float*)d_in[2];
  const float* w1 = (const float*)d_in[3];
  const float* b1 = (const float*)d_in[4];
  const float* w2 = (const float*)d_in[5];
  const float* b2 = (const float*)d_in[6];
  float* out = (float*)d_out;

  const long N = 2048, C = 768, H = 3072;

  // ws: xb + gates + parts(G per-expert fp32) + w1b + w2b + hbuf
  int G = 32;
  for (;;) {
    long need = N * C * 2 + N * 32 * 4 + (long)G * N * C * 4
              + (long)G * C * H * 2 * 2 + N * (long)G * H * 2;
    if ((size_t)need <= ws_size || G == 1) break;
    G >>= 1;
  }

  char* p = (char*)d_ws;
  u16*   xb    = (u16*)p;   p += N * C * 2;
  float* gates = (float*)p; p += N * 32 * 4;
  float* parts = (float*)p; p += (long)G * N * C * 4;
  u16*   w1b   = (u16*)p;   p += (long)G * C * H * 2;
  u16*   w2b   = (u16*)p;   p += (long)G * H * C * 2;
  u16*   hbuf  = (u16*)p;

  // 128 KiB dynamic LDS opt-in. Unconditional: cheap, capture-safe (no stream ops),
  // immune to process-replay resetting function-level attributes.
  hipFuncSetAttribute(reinterpret_cast<const void*>(gemm256<1>),
                      hipFuncAttributeMaxDynamicSharedMemorySize, 131072);
  hipFuncSetAttribute(reinterpret_cast<const void*>(gemm256<2>),
                      hipFuncAttributeMaxDynamicSharedMemorySize, 131072);

  cvt_x_kernel<<<(N * C / 4 + 255) / 256, 256, 0, stream>>>(x, xb, (int)(N * C / 4));
  gate_kernel<<<N / 2, 64, 0, stream>>>(x, gw, gb, gates);
  bias_out_kernel<<<N * C / 256, 256, 0, stream>>>(gates, b2, out);

  const int ngroups = 32 / G;
  for (int g = 0; g < ngroups; ++g) {
    const float* w1g = w1 + (long)g * G * C * H;
    const float* w2g = w2 + (long)g * G * H * C;

    // pack w1 group: K=768 -> 12 ktiles, N=G*H -> 24G ntiles (expert-strided cols)
    dim3 pg1(12, 24 * G);
    pack_b_kernel<<<pg1, 256, 0, stream>>>(w1g, w1b, 12, (int)H, (long)C * H, (int)H);

    // gemm1: hbuf = bf16(gelu(x@w1+b1)). K=768 -> nkt=12, grid 8 x 12G
    gemm256<1><<<dim3(8, 12 * G, 1), 512, 131072, stream>>>(
        xb, C, w1b, 12, 0, 12, (void*)hbuf, (long)G * H, b1 + (long)g * G * H, 0L);

    // pack w2 group: K=G*H -> 48G ktiles, N=768 -> 6 ntiles
    dim3 pg2(48 * G, 6);
    pack_b_kernel<<<pg2, 256, 0, stream>>>(w2g, w2b, 48 * G, 768, 0L, 768);

    // gemm2: parts[z] = h'[:, expert z] @ w2[z]. one expert per z: K=3072 -> nkt=48
    gemm256<2><<<dim3(8, 3, G), 512, 131072, stream>>>(
        hbuf, (long)G * H, w2b, 48 * G, 48, 48, (void*)parts, 768L, nullptr, N * C);

    // out += sum_z gates[:, gG+z] * parts[z]
    reduce_kernel<<<(int)((N * C / 4 + 255) / 256), 256, 0, stream>>>(
        parts, gates, out, G, g * G, (int)(N * C / 4));
  }
}

// Round 3
// 1545.041 us; speedup vs baseline: 1.1017x; 1.0802x over previous
//
#include <hip/hip_runtime.h>
#include <stdint.h>

// CouncilLayer: out[n,c] = sum_e softmax(x@gw+gb)[n,e] * (gelu(x@w1[e]+b1[e]) @ w2[e] + b2[e])[c]
// N=2048 tokens, C=768, E=32, H=3072. fp32 in/out; bf16 MFMA compute.
//
// R5 = R4 (8-phase 256x256 GEMM, counted vmcnt, XOR-swizzled LDS) +
//  - T1 XCD-aware block swizzle inside gemm256: nid=(id%8)*(total/8)+id/8, m-fastest.
//    R4 placed the 8 B-panel-sharing m-blocks on 8 DIFFERENT XCDs (id%8 == bx);
//    now they are co-XCD + temporally adjacent -> staging served from L2.
//  - MODE1 epilogue via per-wave LDS scratch: 128B-contiguous ushort8v stores
//    (R4: scalar u16 stores -> 32B segments -> measured 736MB vs 402MB logical).

typedef unsigned short u16;
typedef __attribute__((ext_vector_type(8))) short short8;     // bf16 MFMA A/B frag
typedef __attribute__((ext_vector_type(8))) unsigned short ushort8v;
typedef __attribute__((ext_vector_type(4))) unsigned short ushort4v;
typedef __attribute__((ext_vector_type(4))) float float4v;

#define DEV __device__ __forceinline__

DEV u16 rne_bf16(float f) {
  union { float f; uint32_t u; } v; v.f = f;
  uint32_t u = v.u;
  u += 0x7FFFu + ((u >> 16) & 1u);
  return (u16)(u >> 16);
}

// branchless erf, Abramowitz-Stegun 7.1.26, |err| <= 1.5e-7
DEV float fast_erf(float x) {
  float ax = __builtin_fabsf(x);
  float t = __builtin_amdgcn_rcpf(__builtin_fmaf(0.3275911f, ax, 1.0f));
  float p = t * (0.254829592f + t * (-0.284496736f + t * (1.421413741f +
            t * (-1.453152027f + t * 1.061405429f))));
  float r = 1.0f - p * __expf(-ax * ax);
  return __builtin_copysignf(r, x);
}

DEV void load_lds16(const void* g, void* l) {
  __builtin_amdgcn_global_load_lds(
      (const __attribute__((address_space(1))) unsigned int*)g,
      (__attribute__((address_space(3))) unsigned int*)l,
      16, 0, 0);
}

// ---------------- small kernels ----------------

__global__ void cvt_x_kernel(const float* __restrict__ x, u16* __restrict__ xb, int n4) {
  int i = blockIdx.x * 256 + threadIdx.x;
  if (i >= n4) return;
  float4v v = *(const float4v*)(x + (size_t)i * 4);
  ushort4v o;
  o[0] = rne_bf16(v[0]); o[1] = rne_bf16(v[1]);
  o[2] = rne_bf16(v[2]); o[3] = rne_bf16(v[3]);
  *(ushort4v*)(xb + (size_t)i * 4) = o;
}

__global__ void gate_kernel(const float* __restrict__ x, const float* __restrict__ gw,
                            const float* __restrict__ gb, float* __restrict__ gates) {
  int lane = threadIdx.x;
  int tok = blockIdx.x * 2 + (lane >> 5);
  int e = lane & 31;
  const float* xr = x + (size_t)tok * 768;
  float s = gb[e];
  #pragma unroll 4
  for (int c = 0; c < 768; ++c) s += xr[c] * gw[c * 32 + e];
  float mx = s;
  #pragma unroll
  for (int o = 16; o >= 1; o >>= 1) mx = fmaxf(mx, __shfl_xor(mx, o, 32));
  float ex = __expf(s - mx);
  float sum = ex;
  #pragma unroll
  for (int o = 16; o >= 1; o >>= 1) sum += __shfl_xor(sum, o, 32);
  gates[tok * 32 + e] = ex / sum;
}

__global__ void bias_out_kernel(const float* __restrict__ gates, const float* __restrict__ b2,
                                float* __restrict__ out) {
  int idx = blockIdx.x * 256 + threadIdx.x;
  int n = idx / 768;
  int c = idx - n * 768;
  const float* g = gates + n * 32;
  float s = 0.f;
  #pragma unroll
  for (int e = 0; e < 32; ++e) s += g[e] * b2[e * 768 + c];
  out[idx] = s;
}

// out += sum_z gates[n, e_base+z] * part[z]   (parts are per-expert, gate applied here in fp32)
__global__ void reduce_kernel(const float* __restrict__ part, const float* __restrict__ gates,
                              float* __restrict__ out, int zn, int e_base, int n4) {
  int i = blockIdx.x * 256 + threadIdx.x;
  if (i >= n4) return;
  int n = (i << 2) / 768;
  const float* g = gates + n * 32 + e_base;
  float4v o = *(const float4v*)(out + (size_t)i * 4);
  #pragma unroll 4
  for (int z = 0; z < zn; ++z) {
    float gz = g[z];
    float4v p = *(const float4v*)(part + (size_t)z * (2048L * 768) + (size_t)i * 4);
    o[0] += gz * p[0]; o[1] += gz * p[1]; o[2] += gz * p[2]; o[3] += gz * p[3];
  }
  *(float4v*)(out + (size_t)i * 4) = o;
}

// pack fp32 [K x N] into bf16 tiles [nt][kt][n(128)][k(64)], 16KB/tile,
// with 16B-chunk XOR swizzle: chunk c of row n stored at slot c^(n&7).
__global__ void pack_b_kernel(const float* __restrict__ in, u16* __restrict__ out,
                              int ktiles, int n_per_e, long e_stride, int row_stride) {
  int kt = blockIdx.x, nt = blockIdx.y;
  int n0 = nt * 128;
  int e = n0 / n_per_e;
  int nl = n0 - e * n_per_e;
  const float* src = in + (long)e * e_stride + (long)kt * 64 * row_stride + nl;

  __shared__ u16 lds[64 * 136];
  int t = threadIdx.x;
  {
    int k = t >> 2, nq = (t & 3) * 32;
    const float* p = src + (long)k * row_stride + nq;
    u16 tmp[32];
    #pragma unroll
    for (int i = 0; i < 32; i += 4) {
      float4v v = *(const float4v*)(p + i);
      tmp[i] = rne_bf16(v[0]); tmp[i + 1] = rne_bf16(v[1]);
      tmp[i + 2] = rne_bf16(v[2]); tmp[i + 3] = rne_bf16(v[3]);
    }
    #pragma unroll
    for (int i = 0; i < 32; i += 8)
      *(ushort8v*)&lds[k * 136 + nq + i] = *(ushort8v*)&tmp[i];
  }
  __syncthreads();
  {
    int n = t >> 1, half = t & 1;
    u16 v[32];
    #pragma unroll
    for (int j = 0; j < 32; ++j) v[j] = lds[(half * 32 + j) * 136 + n];
    u16* tile = out + ((long)nt * ktiles + kt) * 8192 + n * 64;
    int sw = n & 7;
    #pragma unroll
    for (int cc = 0; cc < 4; ++cc) {
      int c = half * 4 + cc;
      *(ushort8v*)(tile + ((c ^ sw) * 8)) = *(ushort8v*)&v[cc * 8];
    }
  }
}

// ---------------- 256x256 8-phase GEMM ----------------
// 8 waves (2M x 4N), per-wave 128x64 output = acc[8][4] 16x16 frags (128 AGPR).
// LDS: dbuf x (A 256x64 + B 256x64) bf16 = 131072 B dynamic.
// A: bf16 row-major [M x Ktot], staged with lane-swizzled global source -> XOR image.
// B: pre-packed swizzled 128x64 tiles; two tiles side by side = linear [256][64] image.
// MODE 1: out = bf16(gelu(acc + b1)) -> hbuf.  MODE 2: fp32 per-expert partial store.
template <int MODE>
__global__ __launch_bounds__(512, 2) void gemm256(
    const u16* __restrict__ A, long lda,
    const u16* __restrict__ Bp, int ktt, int ktb, int nkt,
    void* __restrict__ outp, long ldo,
    const float* __restrict__ b1g, long zstride) {

  extern __shared__ u16 sm[];
  // layout (bytes): [A0 0..32K][B0 32..64K][A1 64..96K][B1 96..128K]
  u16* const Abuf[2] = { sm,         sm + 32768 };
  u16* const Bbuf[2] = { sm + 16384, sm + 49152 };

  const int tid  = threadIdx.x;
  const int wave = tid >> 6, lane = tid & 63;
  const int wr = wave >> 2, wc = wave & 3;           // 2M x 4N wave grid
  const int bh = wave >> 2, w4 = wave & 3;           // B staging: half + quarter
  const int lr = lane >> 3, l8 = lane & 7;           // A staging row/chunk
  const int frow = lane & 15, fq = lane >> 4, fx = lane & 7;

  // T1: XCD-aware swizzle. Default linear id has the 8 B-panel-sharing m-blocks
  // at id%8 = 0..7 -> 8 different XCDs. Remap so XCD k gets a contiguous nid run
  // (m fastest): sharers co-XCD, temporally adjacent, staging hits its L2.
  // Bijective: total is always a multiple of 8 here.
  const int gx = gridDim.x, gy = gridDim.y;
  int id = blockIdx.x + gx * (blockIdx.y + gy * blockIdx.z);
  const int total = gx * gy * (int)gridDim.z;
  id = (id & 7) * (total >> 3) + (id >> 3);
  const int bxi = id % gx;
  const int rest = id / gx;
  const int byi = rest % gy;
  const int bzi = rest / gy;

  const int m0 = bxi * 256;
  const int nt0 = byi * 2;
  const int kt_begin = bzi * ktb;

  // A staging: wave stages rows wave*32 + j*8 + lr; global chunk (l8^lr) -> linear LDS slot l8.
  // (global_load_lds dest = wave-uniform base + lane*16B; image[row][slot] = global[row][slot^(row&7)])
  const u16* gA = A + (long)(m0 + wave * 32 + lr) * lda + (long)kt_begin * 64 + (l8 ^ lr) * 8;
  // B staging: straight 16KB tile copies (pack output already is the swizzled LDS image).
  const u16* gB = Bp + ((long)(nt0 + bh) * ktt + kt_begin) * 8192 + w4 * 2048 + lane * 8;
  u16* const ldsA[2] = { Abuf[0] + wave * 2048, Abuf[1] + wave * 2048 };
  u16* const ldsB[2] = { Bbuf[0] + bh * 8192 + w4 * 2048, Bbuf[1] + bh * 8192 + w4 * 2048 };

  float4v acc[8][4] = {};
  short8 af[4][2], bf[2][2];

#define STAGE(p) { \
    _Pragma("unroll") for (int j = 0; j < 4; ++j) { \
      load_lds16(gA + (long)j * 8 * lda, ldsA[p] + j * 512); \
      load_lds16(gB + j * 512,           ldsB[p] + j * 512); } \
    gA += 64; gB += 8192; }

#define RD_A(p, QM) \
    _Pragma("unroll") for (int mf = 0; mf < 4; ++mf) \
    _Pragma("unroll") for (int ks = 0; ks < 2; ++ks) \
      af[mf][ks] = *(const short8*)&Abuf[p][(wr * 128 + (QM) * 64 + mf * 16 + frow) * 64 + \
                                            (((ks * 4 + fq) ^ fx) * 8)];

#define RD_B(p, QN) \
    _Pragma("unroll") for (int nf = 0; nf < 2; ++nf) \
    _Pragma("unroll") for (int ks = 0; ks < 2; ++ks) \
      bf[nf][ks] = *(const short8*)&Bbuf[p][(wc * 64 + (QN) * 32 + nf * 16 + frow) * 64 + \
                                            (((ks * 4 + fq) ^ fx) * 8)];

#define MMQ(QM, QN) { \
    __builtin_amdgcn_s_barrier(); \
    asm volatile("s_waitcnt lgkmcnt(0)" ::: "memory"); \
    __builtin_amdgcn_sched_barrier(0); \
    __builtin_amdgcn_s_setprio(1); \
    _Pragma("unroll") for (int mf = 0; mf < 4; ++mf) \
    _Pragma("unroll") for (int nf = 0; nf < 2; ++nf) \
    _Pragma("unroll") for (int ks = 0; ks < 2; ++ks) \
      acc[(QM) * 4 + mf][(QN) * 2 + nf] = __builtin_amdgcn_mfma_f32_16x16x32_bf16( \
          af[mf][ks], bf[nf][ks], acc[(QM) * 4 + mf][(QN) * 2 + nf], 0, 0, 0); \
    __builtin_amdgcn_s_setprio(0); \
    __builtin_amdgcn_s_barrier(); }

  // 4 quadrant phases per K-tile; A frags reused across qn, B frags across qm.
#define HALF(p) { RD_A(p, 0); RD_B(p, 0); MMQ(0, 0); \
                  RD_B(p, 1);             MMQ(0, 1); \
                  RD_A(p, 1);             MMQ(1, 1); \
                  RD_B(p, 0);             MMQ(1, 0); }

#define WAITV8 { asm volatile("s_waitcnt vmcnt(8)" ::: "memory"); \
                 __builtin_amdgcn_s_barrier(); __builtin_amdgcn_sched_barrier(0); }
#define WAITV0 { asm volatile("s_waitcnt vmcnt(0)" ::: "memory"); \
                 __builtin_amdgcn_s_barrier(); __builtin_amdgcn_sched_barrier(0); }

  // vmcnt ledger (8 loads per STAGE):
  //   prologue: STAGE(0) STAGE(1)        -> 16 outstanding
  //   loop i:   WAITV8 (tile 2i landed, 8 left) HALF(0) STAGE(0) -> 16
  //             WAITV8 (tile 2i+1 landed)       HALF(1) STAGE(1) -> 16
  //   tail:     WAITV8 HALF(0)  WAITV0 HALF(1)  -> 0
  STAGE(0); STAGE(1);
  const int niter = nkt >> 1;
  for (int i = 0; i < niter - 1; ++i) {
    WAITV8;
    HALF(0);
    STAGE(0);
    WAITV8;
    HALF(1);
    STAGE(1);
  }
  WAITV8; HALF(0);
  WAITV0; HALF(1);

#undef STAGE
#undef RD_A
#undef RD_B
#undef MMQ
#undef HALF
#undef WAITV8
#undef WAITV0

  if (MODE == 1) {
    // Epilogue via per-wave 2KB LDS scratch (Abuf[0] region is dead: all waves are
    // past the final MMQ barrier; each wave touches only its own 2KB).
    // Produces 16B/lane stores, 128B contiguous per 8 lanes per row.
    const int n0 = nt0 * 128;                 // column within [G*H]
    const int e_loc = n0 / 3072;
    const int h0 = n0 - e_loc * 3072;
    const float* be = b1g + (long)e_loc * 3072 + h0 + wc * 64;
    u16* out = (u16*)outp;
    u16* scr = sm + wave * 1024;              // 1024 u16 = 2KB per wave
    float bvv[2][2];
    #pragma unroll
    for (int qn = 0; qn < 2; ++qn)
      #pragma unroll
      for (int nf = 0; nf < 2; ++nf)
        bvv[qn][nf] = be[qn * 32 + nf * 16 + frow];

    #pragma unroll
    for (int qm = 0; qm < 2; ++qm)
      #pragma unroll
      for (int mf = 0; mf < 4; ++mf) {
        // write 16x64 chunk: rows fq*4+r, cols qn*32+nf*16+frow
        #pragma unroll
        for (int qn = 0; qn < 2; ++qn)
          #pragma unroll
          for (int nf = 0; nf < 2; ++nf) {
            const int c = qn * 32 + nf * 16 + frow;
            #pragma unroll
            for (int r = 0; r < 4; ++r) {
              float v = acc[qm * 4 + mf][qn * 2 + nf][r] + bvv[qn][nf];
              v = 0.5f * v * (1.0f + fast_erf(v * 0.70710678118654752440f));
              scr[(fq * 4 + r) * 64 + c] = rne_bf16(v);
            }
          }
        // read back row-major, store 16B/lane (lanes 0..7 -> 128B of row)
        #pragma unroll
        for (int h = 0; h < 2; ++h) {
          const int row = h * 8 + (lane >> 3);
          ushort8v vv = *(const ushort8v*)&scr[row * 64 + (lane & 7) * 8];
          *(ushort8v*)(out + (long)(m0 + wr * 128 + qm * 64 + mf * 16 + row) * ldo
                           + (n0 + wc * 64 + (lane & 7) * 8)) = vv;
        }
      }
  } else {
    float* out = (float*)outp + (long)bzi * zstride;
    const int n0 = nt0 * 128;
    #pragma unroll
    for (int qn = 0; qn < 2; ++qn)
      #pragma unroll
      for (int nf = 0; nf < 2; ++nf) {
        const int ncol = n0 + wc * 64 + qn * 32 + nf * 16 + frow;
        #pragma unroll
        for (int qm = 0; qm < 2; ++qm)
          #pragma unroll
          for (int mf = 0; mf < 4; ++mf) {
            float* op = out + (long)(m0 + wr * 128 + qm * 64 + mf * 16 + fq * 4) * ldo + ncol;
            #pragma unroll
            for (int r = 0; r < 4; ++r) op[(long)r * ldo] = acc[qm * 4 + mf][qn * 2 + nf][r];
          }
      }
  }
}

// ---------------- launch ----------------

extern "C" void kernel_launch(void* const* d_in, const int* in_sizes, int n_in,
                              void* d_out, int out_size, void* d_ws, size_t ws_size,
                              hipStream_t stream) {
  (void)in_sizes; (void)n_in; (void)out_size;
  const float* x  = (const float*)d_in[0];
  const float* gw = (const float*)d_in[1];
  const float* gb = (const float*)d_in[2];
  const float* w1 = (const float*)d_in[3];
  const float* b1 = (const float*)d_in[4];
  const float* w2 = (const float*)d_in[5];
  const float* b2 = (const float*)d_in[6];
  float* out = (float*)d_out;

  const long N = 2048, C = 768, H = 3072;

  // ws: xb + gates + parts(G per-expert fp32) + w1b + w2b + hbuf
  int G = 32;
  for (;;) {
    long need = N * C * 2 + N * 32 * 4 + (long)G * N * C * 4
              + (long)G * C * H * 2 * 2 + N * (long)G * H * 2;
    if ((size_t)need <= ws_size || G == 1) break;
    G >>= 1;
  }

  char* p = (char*)d_ws;
  u16*   xb    = (u16*)p;   p += N * C * 2;
  float* gates = (float*)p; p += N * 32 * 4;
  float* parts = (float*)p; p += (long)G * N * C * 4;
  u16*   w1b   = (u16*)p;   p += (long)G * C * H * 2;
  u16*   w2b   = (u16*)p;   p += (long)G * H * C * 2;
  u16*   hbuf  = (u16*)p;

  // 128 KiB dynamic LDS opt-in. Unconditional: cheap, capture-safe (no stream ops).
  hipFuncSetAttribute(reinterpret_cast<const void*>(gemm256<1>),
                      hipFuncAttributeMaxDynamicSharedMemorySize, 131072);
  hipFuncSetAttribute(reinterpret_cast<const void*>(gemm256<2>),
                      hipFuncAttributeMaxDynamicSharedMemorySize, 131072);

  cvt_x_kernel<<<(N * C / 4 + 255) / 256, 256, 0, stream>>>(x, xb, (int)(N * C / 4));
  gate_kernel<<<N / 2, 64, 0, stream>>>(x, gw, gb, gates);
  bias_out_kernel<<<N * C / 256, 256, 0, stream>>>(gates, b2, out);

  const int ngroups = 32 / G;
  for (int g = 0; g < ngroups; ++g) {
    const float* w1g = w1 + (long)g * G * C * H;
    const float* w2g = w2 + (long)g * G * H * C;

    // pack w1 group: K=768 -> 12 ktiles, N=G*H -> 24G ntiles (expert-strided cols)
    dim3 pg1(12, 24 * G);
    pack_b_kernel<<<pg1, 256, 0, stream>>>(w1g, w1b, 12, (int)H, (long)C * H, (int)H);

    // gemm1: hbuf = bf16(gelu(x@w1+b1)). K=768 -> nkt=12, grid 8 x 12G
    gemm256<1><<<dim3(8, 12 * G, 1), 512, 131072, stream>>>(
        xb, C, w1b, 12, 0, 12, (void*)hbuf, (long)G * H, b1 + (long)g * G * H, 0L);

    // pack w2 group: K=G*H -> 48G ktiles, N=768 -> 6 ntiles
    dim3 pg2(48 * G, 6);
    pack_b_kernel<<<pg2, 256, 0, stream>>>(w2g, w2b, 48 * G, 768, 0L, 768);

    // gemm2: parts[z] = h'[:, expert z] @ w2[z]. one expert per z: K=3072 -> nkt=48
    gemm256<2><<<dim3(8, 3, G), 512, 131072, stream>>>(
        hbuf, (long)G * H, w2b, 48 * G, 48, 48, (void*)parts, 768L, nullptr, N * C);

    // out += sum_z gates[:, gG+z] * parts[z]
    reduce_kernel<<<(int)((N * C / 4 + 255) / 256), 256, 0, stream>>>(
        parts, gates, out, G, g * G, (int)(N * C / 4));
  }
}